// Round 1
// baseline (132.423 us; speedup 1.0000x reference)
//
#include <hip/hip_runtime.h>
#include <hip/hip_bf16.h>

// IGD metric kernel for MI355X (gfx950).
// d2(i,j) = pfsq[i] + xsq[j] + dot(Abf[i], Bbf[j])  where Abf = bf16(-2*pf), Bbf = bf16(x),
// pfsq/xsq computed from the *rounded* values so d2 is an exact squared distance of rounded vectors.
// Main kernel: per-wave persistent A fragments (64 rows), stream B in 32-col chunks via
// v_mfma_f32_32x32x16_bf16, running min of (acc + xsq) per (lane,reg), no LDS / no barriers.

typedef __bf16 bf16x8 __attribute__((ext_vector_type(8)));
typedef float f32x16 __attribute__((ext_vector_type(16)));

#define DIM 64
#define NSPLIT 8
#define NCHUNK 2048   // columns per block
#define MTILE 256     // rows per block (4 waves x 64 rows)

// ---------------- pack: fp32 [rows][64] -> bf16 [rows][64] (+ per-row sum of squares) -------------
// 4 lanes per row, 16 elements each -> coalesced 16B loads/stores.
__global__ void pack_kernel(const float* __restrict__ src, __bf16* __restrict__ dst,
                            float* __restrict__ sq, float scale, float sqScale, int nRows) {
    int gid = blockIdx.x * blockDim.x + threadIdx.x;
    int row = gid >> 2, q = gid & 3;
    if (row >= nRows) return;
    const float* s = src + (size_t)row * DIM + q * 16;
    float partial = 0.f;
    bf16x8 outv[2];
#pragma unroll
    for (int h = 0; h < 2; ++h) {
        float4 v0 = *(const float4*)(s + h * 8);
        float4 v1 = *(const float4*)(s + h * 8 + 4);
        float f[8] = {v0.x, v0.y, v0.z, v0.w, v1.x, v1.y, v1.z, v1.w};
#pragma unroll
        for (int i = 0; i < 8; ++i) {
            __bf16 b = (__bf16)(f[i] * scale);
            outv[h][i] = b;
            float bb = (float)b;
            partial += bb * bb;
        }
    }
    *(bf16x8*)(dst + (size_t)row * DIM + q * 16)     = outv[0];
    *(bf16x8*)(dst + (size_t)row * DIM + q * 16 + 8) = outv[1];
    partial += __shfl_xor(partial, 1);
    partial += __shfl_xor(partial, 2);
    if (q == 0) sq[row] = partial * sqScale;
}

// ---------------- main: fused GEMM + row-min ----------------
// A: bf16(-2*pf) [M][64], B: bf16(x) [N][64], xsq: [N]
// partial[row][nsplit] = min over this split's columns of (xsq[col] - 2*pf[row].x[col])
__global__ __launch_bounds__(256, 2)
void igd_main(const __bf16* __restrict__ A, const __bf16* __restrict__ B,
              const float* __restrict__ xsq, float* __restrict__ partial) {
    const int mTile  = blockIdx.x;
    const int nsplit = blockIdx.y;
    const int lane = threadIdx.x & 63;
    const int wave = threadIdx.x >> 6;
    const int half = lane >> 5;     // 0/1
    const int l31  = lane & 31;
    const int rowBase = mTile * MTILE + wave * 64;

    // Persistent A fragments: 2 row-groups x 4 K-frags.
    // A-operand layout (32x32x16): lane holds A[row = lane&31][k = (lane>>5)*8 + j], j=0..7
    bf16x8 a[2][4];
#pragma unroll
    for (int g = 0; g < 2; ++g) {
        const __bf16* ap = A + (size_t)(rowBase + 32 * g + l31) * DIM + half * 8;
#pragma unroll
        for (int kf = 0; kf < 4; ++kf)
            a[g][kf] = *(const bf16x8*)(ap + kf * 16);
    }

    f32x16 zero, m0, m1;
#pragma unroll
    for (int r = 0; r < 16; ++r) { zero[r] = 0.f; m0[r] = 1e30f; m1[r] = 1e30f; }

    const int colBase0 = nsplit * NCHUNK;
    // B-operand layout: lane holds B[k = (lane>>5)*8 + i][col = lane&31]
    //   = x_bf16[col*64 + (lane>>5)*8 + i]  -> one 16B load per K-frag
    const __bf16* bbase = B + (size_t)(colBase0 + l31) * DIM + half * 8;
    const int CHUNKS = NCHUNK / 32;

    // prefetch chunk 0
    bf16x8 bcur[4];
#pragma unroll
    for (int kf = 0; kf < 4; ++kf) bcur[kf] = *(const bf16x8*)(bbase + kf * 16);
    float xq_cur = xsq[colBase0 + l31];

#pragma unroll 2
    for (int c = 0; c < CHUNKS; ++c) {
        // prefetch next chunk (wrap to 0 on last iter: harmless in-bounds load)
        int cn = (c + 1 < CHUNKS) ? c + 1 : 0;
        const __bf16* nb = bbase + (size_t)cn * 32 * DIM;
        bf16x8 bnext[4];
#pragma unroll
        for (int kf = 0; kf < 4; ++kf) bnext[kf] = *(const bf16x8*)(nb + kf * 16);
        float xq_next = xsq[colBase0 + cn * 32 + l31];

        f32x16 acc0 = __builtin_amdgcn_mfma_f32_32x32x16_bf16(a[0][0], bcur[0], zero, 0, 0, 0);
        f32x16 acc1 = __builtin_amdgcn_mfma_f32_32x32x16_bf16(a[1][0], bcur[0], zero, 0, 0, 0);
#pragma unroll
        for (int kf = 1; kf < 4; ++kf) {
            acc0 = __builtin_amdgcn_mfma_f32_32x32x16_bf16(a[0][kf], bcur[kf], acc0, 0, 0, 0);
            acc1 = __builtin_amdgcn_mfma_f32_32x32x16_bf16(a[1][kf], bcur[kf], acc1, 0, 0, 0);
        }
#pragma unroll
        for (int r = 0; r < 16; ++r) {
            m0[r] = fminf(m0[r], acc0[r] + xq_cur);
            m1[r] = fminf(m1[r], acc1[r] + xq_cur);
        }
#pragma unroll
        for (int kf = 0; kf < 4; ++kf) bcur[kf] = bnext[kf];
        xq_cur = xq_next;
    }

    // cross-lane min over the 32 lanes sharing a row (low 5 lane bits)
#pragma unroll
    for (int mask = 1; mask <= 16; mask <<= 1) {
#pragma unroll
        for (int r = 0; r < 16; ++r) {
            m0[r] = fminf(m0[r], __shfl_xor(m0[r], mask));
            m1[r] = fminf(m1[r], __shfl_xor(m1[r], mask));
        }
    }
    if (l31 == 0) {
        // C/D layout: row = (r&3) + 8*(r>>2) + 4*(lane>>5)
#pragma unroll
        for (int r = 0; r < 16; ++r) {
            int row0 = rowBase + (r & 3) + 8 * (r >> 2) + 4 * half;
            partial[(size_t)row0 * NSPLIT + nsplit] = m0[r];
            partial[(size_t)(row0 + 32) * NSPLIT + nsplit] = m1[r];
        }
    }
}

// ---------------- reduce: min over splits, sqrt, mean ----------------
__global__ void reduce_kernel(const float* __restrict__ partial, const float* __restrict__ pfsq,
                              float* __restrict__ out, int M, float invM) {
    int row = blockIdx.x * blockDim.x + threadIdx.x;
    float v = 0.f;
    if (row < M) {
        const float* p = partial + (size_t)row * NSPLIT;
        float mn = 3.4e38f;
#pragma unroll
        for (int s = 0; s < NSPLIT; ++s) mn = fminf(mn, p[s]);
        float d2 = mn + pfsq[row];
        v = sqrtf(fmaxf(d2, 0.f)) * invM;
    }
#pragma unroll
    for (int m = 1; m < 64; m <<= 1) v += __shfl_xor(v, m);
    __shared__ float wsum[4];
    int lane = threadIdx.x & 63, w = threadIdx.x >> 6;
    if (lane == 0) wsum[w] = v;
    __syncthreads();
    if (threadIdx.x == 0) atomicAdd(out, wsum[0] + wsum[1] + wsum[2] + wsum[3]);
}

extern "C" void kernel_launch(void* const* d_in, const int* in_sizes, int n_in,
                              void* d_out, int out_size, void* d_ws, size_t ws_size,
                              hipStream_t stream) {
    const float* x  = (const float*)d_in[0];   // [N, 64]
    const float* pf = (const float*)d_in[1];   // [M, 64]
    const int N = in_sizes[0] / DIM;
    const int M = in_sizes[1] / DIM;

    char* ws = (char*)d_ws;
    __bf16* Bb   = (__bf16*)ws;                                   // N*64*2 bytes
    __bf16* Ab   = (__bf16*)(ws + (size_t)N * DIM * 2);           // M*64*2 bytes
    float*  xsq  = (float*)(ws + (size_t)(N + M) * DIM * 2);      // N floats
    float*  pfsq = xsq + N;                                       // M floats
    float*  part = pfsq + M;                                      // M*NSPLIT floats

    hipMemsetAsync(d_out, 0, sizeof(float), stream);
    pack_kernel<<<dim3((N * 4) / 256), 256, 0, stream>>>(x,  Bb, xsq,  1.f,  1.f,  N);
    pack_kernel<<<dim3((M * 4) / 256), 256, 0, stream>>>(pf, Ab, pfsq, -2.f, 0.25f, M);
    igd_main<<<dim3(M / MTILE, N / NCHUNK), 256, 0, stream>>>(Ab, Bb, xsq, part);
    reduce_kernel<<<dim3((M + 255) / 256), 256, 0, stream>>>(part, pfsq, (float*)d_out, M, 1.f / (float)M);
}